// Round 3
// baseline (179.152 us; speedup 1.0000x reference)
//
#include <hip/hip_runtime.h>

// CrossAttention with LoRA (folded). B=16, C=64, hw=4096, L=77, COND=768, HEADS=8, dh=8.
// Round 3: megattn with one WAVE per head. k/v and all weights are read via
// wave-uniform addresses (scalar K$ path), eliminating the per-CU LDS-unit
// bottleneck in the attention loop. LDS used only for the ao head-gather
// (pad-66 float2 layout: 8B-aligned, <=2-way bank aliasing = free).
// Pipeline: prep_weights -> kvproj (split-K) -> kvreduce -> megattn.

#define HW   4096
#define CHN  64
#define LSEQ 77
#define CD   768
#define NB   16
#define PAD  66

// workspace float offsets
#define OFF_WQ 0
#define OFF_WK 4096
#define OFF_WV 53248
#define OFF_WO 102400
#define OFF_K  106496
#define OFF_V  185344
#define OFF_PA 264192   // partials [2][12][16][77*64]

#define QF 0.51011784563163f  // SCALE * log2(e) = 8^-0.5 * 1.442695...

__global__ __launch_bounds__(256) void prep_weights(
    const float* __restrict__ Wq, const float* __restrict__ Aq, const float* __restrict__ Bq,
    const float* __restrict__ Wk, const float* __restrict__ Ak, const float* __restrict__ Bk,
    const float* __restrict__ Wv, const float* __restrict__ Av, const float* __restrict__ Bv,
    const float* __restrict__ Wo, const float* __restrict__ Ao, const float* __restrict__ Bo,
    float* __restrict__ ws) {
  int idx = blockIdx.x * 256 + threadIdx.x;   // 416*256 = 106496 exact
  const float *W, *A, *Bm;
  float* out;
  int in_d, local;
  float scale = 1.0f;
  if (idx < 4096)        { W = Wq; A = Aq; Bm = Bq; out = ws + OFF_WQ; in_d = 64;  local = idx; scale = QF; }
  else if (idx < 53248)  { W = Wk; A = Ak; Bm = Bk; out = ws + OFF_WK; in_d = 768; local = idx - 4096; }
  else if (idx < 102400) { W = Wv; A = Av; Bm = Bv; out = ws + OFF_WV; in_d = 768; local = idx - 53248; }
  else                   { W = Wo; A = Ao; Bm = Bo; out = ws + OFF_WO; in_d = 64;  local = idx - 102400; }
  int co = local & 63;
  int c  = local >> 6;
  float val = W[co * in_d + c];
  #pragma unroll
  for (int r = 0; r < 8; r++) val += Bm[co * 8 + r] * A[r * in_d + c];
  out[local] = val * scale;   // local == c*64+co : W_eff^T [in][out]
}

// split-K partial projection of cond -> k/v. grid (12 kchunks, 2 kv, 16 b), block 128 (lane = l).
__global__ __launch_bounds__(128, 2) void kvproj(
    const float* __restrict__ cond,  // [16][77][768]
    const float* __restrict__ wkT,   // [768][64]
    const float* __restrict__ wvT,
    float* __restrict__ part) {      // [2][12][16][77*64]
  int chunk = blockIdx.x;
  int kv    = blockIdx.y;
  int b     = blockIdx.z;
  int l     = threadIdx.x;
  if (l >= LSEQ) return;
  const float* wT = kv ? wvT : wkT;
  int c0 = chunk * 64;
  const float* xr = cond + (b * LSEQ + l) * CD + c0;
  float zr[64];
  #pragma unroll
  for (int i = 0; i < 16; i++) {
    float4 t4 = ((const float4*)xr)[i];
    zr[4*i] = t4.x; zr[4*i+1] = t4.y; zr[4*i+2] = t4.z; zr[4*i+3] = t4.w;
  }
  float acc[64];
  #pragma unroll
  for (int co = 0; co < 64; co++) acc[co] = 0.f;
  #pragma unroll 4
  for (int c = 0; c < 64; c++) {
    float zv = zr[c];
    #pragma unroll
    for (int co = 0; co < 64; co++) acc[co] = fmaf(zv, wT[(c0 + c) * 64 + co], acc[co]);
  }
  float* pout = part + (((kv * 12 + chunk) * NB + b) * LSEQ + l) * 64;
  #pragma unroll
  for (int i = 0; i < 16; i++) {
    ((float4*)pout)[i] = make_float4(acc[4*i], acc[4*i+1], acc[4*i+2], acc[4*i+3]);
  }
}

__global__ __launch_bounds__(256) void kvreduce(
    const float* __restrict__ part,
    const float* __restrict__ bk, const float* __restrict__ bv,
    float* __restrict__ kbuf, float* __restrict__ vbuf) {
  int idx = blockIdx.x * 256 + threadIdx.x;  // 616*256 = 157696 exact
  int kv = idx / (NB * LSEQ * 64);
  int r  = idx - kv * (NB * LSEQ * 64);
  int co = idx & 63;
  float val = kv ? bv[co] : bk[co];
  #pragma unroll
  for (int ch = 0; ch < 12; ch++)
    val += part[(kv * 12 + ch) * (NB * LSEQ * 64) + r];
  (kv ? vbuf : kbuf)[r] = val;
}

// Fused q-proj + attention + o-proj, one wave per head.
// grid (64 ptiles of 64 px, 16 b), block 512 (8 waves). lane = px, wave = head.
// All weight/k/v reads are wave-uniform -> scalar path; no LDS in hot loop.
__global__ __launch_bounds__(512, 4) void megattn(
    const float* __restrict__ z,     // [16][64][4096]
    const float* __restrict__ wqT,   // [64][64] [c][co], pre-scaled by QF
    const float* __restrict__ bq,
    const float* __restrict__ kbuf,  // [16][77][64]
    const float* __restrict__ vbuf,
    const float* __restrict__ woT,   // [64][64] [c][co]
    const float* __restrict__ bo,
    float* __restrict__ out) {       // [16][64][4096]
  __shared__ float ao[64 * PAD];     // 16896 B
  int b  = blockIdx.y;
  int p0 = blockIdx.x * 64;
  int t  = threadIdx.x;
  int h  = __builtin_amdgcn_readfirstlane(t >> 6);  // wave index == head (uniform)
  int px = t & 63;

  // ---- Q phase: q[px][8h..8h+7]; weights wave-uniform -> s_load ----
  float q[8];
  #pragma unroll
  for (int d = 0; d < 8; d++) q[d] = bq[8 * h + d] * QF;
  {
    const float* zb = z + b * (CHN * HW) + p0 + px;
    const float* wq = wqT + 8 * h;
    #pragma unroll 8
    for (int c = 0; c < 64; c++) {
      float zv = zb[c * HW];
      #pragma unroll
      for (int d = 0; d < 8; d++) q[d] = fmaf(zv, wq[c * 64 + d], q[d]);
    }
  }

  // ---- Attention: k/v wave-uniform (scalar loads); exp2, no max-sub (bounded logits) ----
  float acc[8];
  float li = 0.f;
  #pragma unroll
  for (int d = 0; d < 8; d++) acc[d] = 0.f;
  {
    const float* kb = kbuf + b * (LSEQ * 64) + 8 * h;
    const float* vb = vbuf + b * (LSEQ * 64) + 8 * h;
    #pragma unroll 7
    for (int j = 0; j < LSEQ; j++) {
      float kf[8], vf[8];
      #pragma unroll
      for (int d = 0; d < 8; d++) kf[d] = kb[j * 64 + d];
      #pragma unroll
      for (int d = 0; d < 8; d++) vf[d] = vb[j * 64 + d];
      float s = q[0] * kf[0];
      #pragma unroll
      for (int d = 1; d < 8; d++) s = fmaf(q[d], kf[d], s);
      float e = __builtin_amdgcn_exp2f(s);
      li += e;
      #pragma unroll
      for (int d = 0; d < 8; d++) acc[d] = fmaf(e, vf[d], acc[d]);
    }
  }

  // ---- ao gather: [px][PAD=66] float2 stores (8B aligned, 2-way alias = free) ----
  {
    float inv = 1.0f / li;
    #pragma unroll
    for (int d = 0; d < 8; d += 2)
      *(float2*)(ao + px * PAD + 8 * h + d) = make_float2(acc[d] * inv, acc[d + 1] * inv);
  }
  __syncthreads();

  // ---- O phase: out[8h+i][px] = ao[px][:] . woT[:][8h+i] + bo; weights scalar ----
  {
    float o[8];
    #pragma unroll
    for (int i = 0; i < 8; i++) o[i] = bo[8 * h + i];
    const float* wo = woT + 8 * h;
    const float* aor = ao + px * PAD;
    #pragma unroll 8
    for (int c = 0; c < 64; c += 2) {
      float2 a2 = *(const float2*)(aor + c);
      #pragma unroll
      for (int i = 0; i < 8; i++) o[i] = fmaf(a2.x, wo[c * 64 + i], o[i]);
      #pragma unroll
      for (int i = 0; i < 8; i++) o[i] = fmaf(a2.y, wo[(c + 1) * 64 + i], o[i]);
    }
    float* ob = out + b * (CHN * HW) + p0 + px;
    #pragma unroll
    for (int i = 0; i < 8; i++) ob[(8 * h + i) * HW] = o[i];
  }
}

extern "C" void kernel_launch(void* const* d_in, const int* in_sizes, int n_in,
                              void* d_out, int out_size, void* d_ws, size_t ws_size,
                              hipStream_t stream) {
  const float* z    = (const float*)d_in[0];
  const float* cond = (const float*)d_in[1];
  const float* Wq = (const float*)d_in[2];  const float* bq = (const float*)d_in[3];
  const float* Aq = (const float*)d_in[4];  const float* Bq = (const float*)d_in[5];
  const float* Wk = (const float*)d_in[6];  const float* bk = (const float*)d_in[7];
  const float* Ak = (const float*)d_in[8];  const float* Bk = (const float*)d_in[9];
  const float* Wv = (const float*)d_in[10]; const float* bv = (const float*)d_in[11];
  const float* Av = (const float*)d_in[12]; const float* Bv = (const float*)d_in[13];
  const float* Wo = (const float*)d_in[14]; const float* bo = (const float*)d_in[15];
  const float* Ao = (const float*)d_in[16]; const float* Bo = (const float*)d_in[17];
  float* ws  = (float*)d_ws;
  float* out = (float*)d_out;

  prep_weights<<<416, 256, 0, stream>>>(Wq, Aq, Bq, Wk, Ak, Bk, Wv, Av, Bv, Wo, Ao, Bo, ws);
  kvproj<<<dim3(12, 2, 16), 128, 0, stream>>>(cond, ws + OFF_WK, ws + OFF_WV, ws + OFF_PA);
  kvreduce<<<616, 256, 0, stream>>>(ws + OFF_PA, bk, bv, ws + OFF_K, ws + OFF_V);
  megattn<<<dim3(64, 16), 512, 0, stream>>>(z, ws + OFF_WQ, bq, ws + OFF_K, ws + OFF_V,
                                            ws + OFF_WO, bo, out);
}